// Round 4
// baseline (290.685 us; speedup 1.0000x reference)
//
#include <hip/hip_runtime.h>
#include <cstdint>
#include <cstddef>

#define N_INST 200
#define HWPIX (448 * 448)        // 200704 pixels per mask
#define W64 3136                 // uint64 words per packed mask
#define W16 12544                // uint16 words per packed mask
#define SIGMA 2.0f
#define NCHUNK 4                 // K-split factor in pair kernel
#define NTILE 1275               // triangular 4x4 tiles over a 50x50 tile grid

// workspace layout (bytes)
#define OFF_P   5017600                        // after packed (200*3136*8)
#define P_SLAB  (N_INST * N_INST)              // ints per partial-count slab
#define OFF_SP  (OFF_P + NCHUNK * P_SLAB * 4)  // per-chunk per-mask popcounts
#define OFF_DT  (OFF_SP + NCHUNK * 256 * 4)    // DTf[j*200+i] fp32, i<j only

// ---------------------------------------------------------------------------
// K1: bitpack. grid (49, 200); thread -> 4x float4 = 16 px -> one uint16.
// Little-endian layout makes the uint16 array bit-identical to uint64 words.
// ---------------------------------------------------------------------------
__global__ void pack_kernel(const float* __restrict__ seg,
                            uint16_t* __restrict__ packed16) {
    const int mask = blockIdx.y;
    const int tid  = threadIdx.x;
    const size_t base = (size_t)mask * HWPIX + (size_t)blockIdx.x * 4096 + (size_t)tid * 16;
    const float4* s4 = (const float4*)(seg + base);
    float4 v0 = s4[0], v1 = s4[1], v2 = s4[2], v3 = s4[3];
    uint32_t m = 0;
    m |= (v0.x > 0.5f) ? 1u << 0  : 0u;  m |= (v0.y > 0.5f) ? 1u << 1  : 0u;
    m |= (v0.z > 0.5f) ? 1u << 2  : 0u;  m |= (v0.w > 0.5f) ? 1u << 3  : 0u;
    m |= (v1.x > 0.5f) ? 1u << 4  : 0u;  m |= (v1.y > 0.5f) ? 1u << 5  : 0u;
    m |= (v1.z > 0.5f) ? 1u << 6  : 0u;  m |= (v1.w > 0.5f) ? 1u << 7  : 0u;
    m |= (v2.x > 0.5f) ? 1u << 8  : 0u;  m |= (v2.y > 0.5f) ? 1u << 9  : 0u;
    m |= (v2.z > 0.5f) ? 1u << 10 : 0u;  m |= (v2.w > 0.5f) ? 1u << 11 : 0u;
    m |= (v3.x > 0.5f) ? 1u << 12 : 0u;  m |= (v3.y > 0.5f) ? 1u << 13 : 0u;
    m |= (v3.z > 0.5f) ? 1u << 14 : 0u;  m |= (v3.w > 0.5f) ? 1u << 15 : 0u;
    packed16[(size_t)mask * W16 + blockIdx.x * 256 + tid] = (uint16_t)m;
}

// ---------------------------------------------------------------------------
// K2: pairwise intersection counts, 4x4 tile per wave, K-split by NCHUNK.
// 1275 tiles x 4 chunks = 5100 waves (~5/SIMD -> latency hiding).
// Off-diagonal cells -> P[chunk][j][i]; diagonal cells (i==j) are the
// per-chunk per-mask popcounts -> SP[chunk][i]  (sums for free, no atomics).
// Wave-sums fit 16 bits (<= 13 iters * 64 bits * 64 lanes = 53248 < 65536),
// so pairs are packed 2-per-int for a 48-shfl butterfly instead of 96.
// (Packed add is exact mod 2^32: low+high*2^16 < 2^32.)
// ---------------------------------------------------------------------------
__global__ void pair_kernel(const uint64_t* __restrict__ packed,
                            int* __restrict__ P,
                            int* __restrict__ SP) {
    const int wt   = blockIdx.x * 4 + (threadIdx.x >> 6);   // 0..5099
    const int lane = threadIdx.x & 63;
    const int t     = wt >> 2;       // tile id 0..1274
    const int chunk = wt & 3;

    // decode triangular tile id: t = jt*(jt+1)/2 + it, 0 <= it <= jt <= 49
    int jt = (int)((sqrtf((float)(8 * t + 1)) - 1.0f) * 0.5f);
    while ((jt + 1) * (jt + 2) / 2 <= t) ++jt;
    while (jt * (jt + 1) / 2 > t) --jt;
    const int it = t - jt * (jt + 1) / 2;
    const int i0 = 4 * it, j0 = 4 * jt;

    const int ks = (chunk * 49) >> 2;          // 0,12,24,36
    const int ke = ((chunk + 1) * 49) >> 2;    // 12,24,36,49

    const uint64_t* A = packed + (size_t)i0 * W64;
    const uint64_t* B = packed + (size_t)j0 * W64;

    int c[16];
#pragma unroll
    for (int x = 0; x < 16; ++x) c[x] = 0;

    for (int kb = ks; kb < ke; ++kb) {
        const int k = kb * 64 + lane;
        uint64_t a0 = A[k], a1 = A[k + W64], a2 = A[k + 2 * W64], a3 = A[k + 3 * W64];
        uint64_t b0 = B[k], b1 = B[k + W64], b2 = B[k + 2 * W64], b3 = B[k + 3 * W64];
        c[0]  += __popcll(a0 & b0); c[1]  += __popcll(a0 & b1);
        c[2]  += __popcll(a0 & b2); c[3]  += __popcll(a0 & b3);
        c[4]  += __popcll(a1 & b0); c[5]  += __popcll(a1 & b1);
        c[6]  += __popcll(a1 & b2); c[7]  += __popcll(a1 & b3);
        c[8]  += __popcll(a2 & b0); c[9]  += __popcll(a2 & b1);
        c[10] += __popcll(a2 & b2); c[11] += __popcll(a2 & b3);
        c[12] += __popcll(a3 & b0); c[13] += __popcll(a3 & b1);
        c[14] += __popcll(a3 & b2); c[15] += __popcll(a3 & b3);
    }

    // pack two counts per int, butterfly-reduce
    int p[8];
#pragma unroll
    for (int m = 0; m < 8; ++m) p[m] = c[2 * m] + (c[2 * m + 1] << 16);
#pragma unroll
    for (int off = 1; off < 64; off <<= 1) {
#pragma unroll
        for (int m = 0; m < 8; ++m) p[m] += __shfl_xor(p[m], off, 64);
    }

    if (lane == 0) {
#pragma unroll
        for (int r = 0; r < 4; ++r) {
#pragma unroll
            for (int cc = 0; cc < 4; ++cc) {
                const int idx = r * 4 + cc;
                const int val = (idx & 1) ? (int)(((unsigned)p[idx >> 1]) >> 16)
                                          : (p[idx >> 1] & 0xFFFF);
                const int i = i0 + r, j = j0 + cc;
                if (i < j)       P[chunk * P_SLAB + j * N_INST + i] = val;
                else if (i == j) SP[chunk * 256 + i] = val;   // popc(a&a)=|mask|
            }
        }
    }
}

// ---------------------------------------------------------------------------
// K3: reduce chunk partials -> IoU * same_label, transposed: DTf[j*200+i]
//     holds decay_iou[i][j] for i<j.
// ---------------------------------------------------------------------------
__global__ void iou_kernel(const int* __restrict__ P,
                           const int* __restrict__ SP,
                           const int* __restrict__ labels,
                           float* __restrict__ DTf) {
    const int j = blockIdx.x;
    const int sj = SP[j] + SP[256 + j] + SP[512 + j] + SP[768 + j];
    const int lj = labels[j];
    for (int i = threadIdx.x; i < j; i += 64) {
        const int inter = P[j * N_INST + i] + P[P_SLAB + j * N_INST + i]
                        + P[2 * P_SLAB + j * N_INST + i] + P[3 * P_SLAB + j * N_INST + i];
        const int si = SP[i] + SP[256 + i] + SP[512 + i] + SP[768 + i];
        const float iou = (float)inter / (float)(si + sj - inter);
        DTf[j * N_INST + i] = (labels[i] == lj) ? iou : 0.0f;
    }
}

// ---------------------------------------------------------------------------
// K4: comp[t] = max_i decay_iou[i][t] = max_{i<t} DTf[t*200+i]  (COLUMN max of
//     decay_iou = ROW scan of DTf — this was the round-3 bug, indices were
//     transposed). Then out[t] = score_t *
//     exp(SIGMA * min_i( comp_i^2 - (i<t ? DTf[t*200+i] : 0)^2 )).
// (min of exp == exp of min.) Single block; DTf is 160 KB, L2-hot.
// ---------------------------------------------------------------------------
__global__ void finalize_kernel(const float* __restrict__ DTf,
                                const float* __restrict__ scores,
                                float* __restrict__ out) {
    __shared__ float comp[N_INST];
    const int t = threadIdx.x;
    if (t < N_INST) {
        const float* row = DTf + (size_t)t * N_INST;
        float m = 0.0f;                       // empty column -> 0 (triu zeros)
        for (int i = 0; i < t; ++i) m = fmaxf(m, row[i]);
        comp[t] = m;
    }
    __syncthreads();
    if (t < N_INST) {
        const float* row = DTf + (size_t)t * N_INST;
        float mn = 3.4e38f;
        for (int i = 0; i < N_INST; ++i) {
            const float ci = comp[i];
            float v = ci * ci;
            if (i < t) { const float d = row[i]; v -= d * d; }
            mn = fminf(mn, v);
        }
        out[t] = scores[t] * expf(SIGMA * mn);
    }
}

extern "C" void kernel_launch(void* const* d_in, const int* in_sizes, int n_in,
                              void* d_out, int out_size, void* d_ws, size_t ws_size,
                              hipStream_t stream) {
    const float* seg    = (const float*)d_in[0];   // (200,448,448) fp32 binary
    const float* scores = (const float*)d_in[1];   // (200,) fp32
    const int*   labels = (const int*)d_in[2];     // (200,) int32
    float* out = (float*)d_out;                    // (200,) fp32

    uint64_t* packed   = (uint64_t*)d_ws;
    uint16_t* packed16 = (uint16_t*)d_ws;
    int*      P        = (int*)((char*)d_ws + OFF_P);
    int*      SP       = (int*)((char*)d_ws + OFF_SP);
    float*    DTf      = (float*)((char*)d_ws + OFF_DT);

    {
        dim3 grid(49, N_INST);
        pack_kernel<<<grid, 256, 0, stream>>>(seg, packed16);
    }
    pair_kernel<<<NTILE, 256, 0, stream>>>(packed, P, SP);      // 5100 waves
    iou_kernel<<<N_INST, 64, 0, stream>>>(P, SP, labels, DTf);
    finalize_kernel<<<1, 256, 0, stream>>>(DTf, scores, out);
}

// Round 5
// 253.110 us; speedup vs baseline: 1.1485x; 1.1485x over previous
//
#include <hip/hip_runtime.h>
#include <cstdint>
#include <cstddef>

#define N_INST 200
#define HWPIX (448 * 448)        // 200704 pixels per mask
#define W64 3136                 // uint64 words per packed mask
#define W16 12544                // uint16 words per packed mask
#define SIGMA 2.0f
#define NCHUNK 8                 // K-split factor in pair kernel
#define NTILE 325                // triangular 8x8 tiles over a 25x25 tile grid

// workspace layout (bytes)
#define P_SLAB  (N_INST * N_INST)              // ints per partial-count slab
#define OFF_P   5017600                        // after packed (200*3136*8)
#define OFF_SP  (OFF_P + NCHUNK * P_SLAB * 4)  // per-chunk per-mask popcounts
#define OFF_DT  (OFF_SP + NCHUNK * 256 * 4)    // DTf[j*200+i] fp32, i<j only
#define OFF_CMP (OFF_DT + N_INST * N_INST * 4) // comp[200] fp32

// ---------------------------------------------------------------------------
// K1: bitpack. grid (49, 200); thread -> 4x float4 = 16 px -> one uint16.
// Little-endian layout makes the uint16 array bit-identical to uint64 words.
// At the 160.6 MB input-read roofline (~26 us).
// ---------------------------------------------------------------------------
__global__ void pack_kernel(const float* __restrict__ seg,
                            uint16_t* __restrict__ packed16) {
    const int mask = blockIdx.y;
    const int tid  = threadIdx.x;
    const size_t base = (size_t)mask * HWPIX + (size_t)blockIdx.x * 4096 + (size_t)tid * 16;
    const float4* s4 = (const float4*)(seg + base);
    float4 v0 = s4[0], v1 = s4[1], v2 = s4[2], v3 = s4[3];
    uint32_t m = 0;
    m |= (v0.x > 0.5f) ? 1u << 0  : 0u;  m |= (v0.y > 0.5f) ? 1u << 1  : 0u;
    m |= (v0.z > 0.5f) ? 1u << 2  : 0u;  m |= (v0.w > 0.5f) ? 1u << 3  : 0u;
    m |= (v1.x > 0.5f) ? 1u << 4  : 0u;  m |= (v1.y > 0.5f) ? 1u << 5  : 0u;
    m |= (v1.z > 0.5f) ? 1u << 6  : 0u;  m |= (v1.w > 0.5f) ? 1u << 7  : 0u;
    m |= (v2.x > 0.5f) ? 1u << 8  : 0u;  m |= (v2.y > 0.5f) ? 1u << 9  : 0u;
    m |= (v2.z > 0.5f) ? 1u << 10 : 0u;  m |= (v2.w > 0.5f) ? 1u << 11 : 0u;
    m |= (v3.x > 0.5f) ? 1u << 12 : 0u;  m |= (v3.y > 0.5f) ? 1u << 13 : 0u;
    m |= (v3.z > 0.5f) ? 1u << 14 : 0u;  m |= (v3.w > 0.5f) ? 1u << 15 : 0u;
    packed16[(size_t)mask * W16 + blockIdx.x * 256 + tid] = (uint16_t)m;
}

// ---------------------------------------------------------------------------
// K2: pairwise intersection counts, 8x8 tile per wave, K-split by NCHUNK=8.
// 325 tiles x 8 chunks = 2600 waves; 16 stream-loads feed 64 AND+POPC pairs
// per iteration (traffic 256 MB -> 126 MB vs 4x4 tiles).
// Off-diagonal cells -> P[chunk][j][i]; diagonal (i==j) -> SP[chunk][i]
// (per-chunk per-mask popcounts for free, no atomics, no zero-init).
// Wave-sums fit 16 bits (<= 7 iters * 64 bits * 64 lanes = 28672 < 65536):
// counts packed 2-per-int -> 32x6=192-shfl butterfly instead of 384.
// ---------------------------------------------------------------------------
__global__ void pair_kernel(const uint64_t* __restrict__ packed,
                            int* __restrict__ P,
                            int* __restrict__ SP) {
    const int wt   = blockIdx.x * 4 + (threadIdx.x >> 6);   // 0..2599
    const int lane = threadIdx.x & 63;
    const int t     = wt >> 3;       // tile id 0..324
    const int chunk = wt & 7;

    // decode triangular tile id: t = jt*(jt+1)/2 + it, 0 <= it <= jt <= 24
    int jt = (int)((sqrtf((float)(8 * t + 1)) - 1.0f) * 0.5f);
    while ((jt + 1) * (jt + 2) / 2 <= t) ++jt;
    while (jt * (jt + 1) / 2 > t) --jt;
    const int it = t - jt * (jt + 1) / 2;
    const int i0 = 8 * it, j0 = 8 * jt;

    const int ks = (chunk * 49) >> 3;          // 0,6,12,18,24,30,36,42
    const int ke = ((chunk + 1) * 49) >> 3;    // 6,...,42,49

    const uint64_t* A = packed + (size_t)i0 * W64;
    const uint64_t* B = packed + (size_t)j0 * W64;

    int c[64];
#pragma unroll
    for (int x = 0; x < 64; ++x) c[x] = 0;

    for (int kb = ks; kb < ke; ++kb) {
        const int k = kb * 64 + lane;
        uint64_t a[8], b[8];
#pragma unroll
        for (int r = 0; r < 8; ++r) { a[r] = A[k + r * W64]; b[r] = B[k + r * W64]; }
#pragma unroll
        for (int r = 0; r < 8; ++r)
#pragma unroll
            for (int cc = 0; cc < 8; ++cc)
                c[r * 8 + cc] += __popcll(a[r] & b[cc]);
    }

    // pack two counts per int, butterfly-reduce (exact: low+high*2^16 < 2^32)
    int p[32];
#pragma unroll
    for (int m = 0; m < 32; ++m) p[m] = c[2 * m] + (c[2 * m + 1] << 16);
#pragma unroll
    for (int off = 1; off < 64; off <<= 1) {
#pragma unroll
        for (int m = 0; m < 32; ++m) p[m] += __shfl_xor(p[m], off, 64);
    }

    if (lane == 0) {
#pragma unroll
        for (int r = 0; r < 8; ++r) {
#pragma unroll
            for (int cc = 0; cc < 8; ++cc) {
                const int idx = r * 8 + cc;
                const int val = (idx & 1) ? (int)(((unsigned)p[idx >> 1]) >> 16)
                                          : (p[idx >> 1] & 0xFFFF);
                const int i = i0 + r, j = j0 + cc;
                if (i < j)       P[chunk * P_SLAB + j * N_INST + i] = val;
                else if (i == j) SP[chunk * 256 + i] = val;   // popc(a&a)=|mask|
            }
        }
    }
}

// ---------------------------------------------------------------------------
// K3: reduce chunk partials -> IoU * same_label, transposed storage:
//     DTf[j*200+i] holds decay_iou[i][j] for i<j.
// ---------------------------------------------------------------------------
__global__ void iou_kernel(const int* __restrict__ P,
                           const int* __restrict__ SP,
                           const int* __restrict__ labels,
                           float* __restrict__ DTf) {
    const int j = blockIdx.x;
    int sj = 0;
#pragma unroll
    for (int cch = 0; cch < NCHUNK; ++cch) sj += SP[cch * 256 + j];
    const int lj = labels[j];
    for (int i = threadIdx.x; i < j; i += 64) {
        int inter = 0;
#pragma unroll
        for (int cch = 0; cch < NCHUNK; ++cch)
            inter += P[cch * P_SLAB + j * N_INST + i];
        int si = 0;
#pragma unroll
        for (int cch = 0; cch < NCHUNK; ++cch) si += SP[cch * 256 + i];
        const float iou = (float)inter / (float)(si + sj - inter);
        DTf[j * N_INST + i] = (labels[i] == lj) ? iou : 0.0f;
    }
}

// ---------------------------------------------------------------------------
// K4a: comp[j] = max_i decay_iou[i][j] = max_{i<j} DTf[j*200+i].
// 200 blocks x 64 threads, coalesced row reads. (Round-4's single-block
// fused version serialized ~256 cache lines per load on one CU — regression.)
// ---------------------------------------------------------------------------
__global__ void comp_kernel(const float* __restrict__ DTf,
                            float* __restrict__ comp) {
    const int j = blockIdx.x;
    const int t = threadIdx.x;
    const float* row = DTf + (size_t)j * N_INST;
    float m = 0.0f;                        // empty column (j=0) -> 0
    for (int i = t; i < j; i += 64) m = fmaxf(m, row[i]);
#pragma unroll
    for (int off = 1; off < 64; off <<= 1) m = fmaxf(m, __shfl_xor(m, off, 64));
    if (t == 0) comp[j] = m;
}

// ---------------------------------------------------------------------------
// K4b: out[j] = scores[j] * exp(SIGMA * min_i(comp[i]^2 - d_ij^2)),
//      d_ij = decay_iou[i][j] = (i<j ? DTf[j*200+i] : 0).
// (min of exp == exp of min; exp monotone.) Coalesced row reads.
// ---------------------------------------------------------------------------
__global__ void finalize_kernel(const float* __restrict__ DTf,
                                const float* __restrict__ comp,
                                const float* __restrict__ scores,
                                float* __restrict__ out) {
    const int j = blockIdx.x;
    const int t = threadIdx.x;
    const float* row = DTf + (size_t)j * N_INST;
    float mn = 3.4e38f;
    for (int i = t; i < N_INST; i += 64) {
        const float ci = comp[i];
        float v = ci * ci;
        if (i < j) { const float d = row[i]; v -= d * d; }
        mn = fminf(mn, v);
    }
#pragma unroll
    for (int off = 1; off < 64; off <<= 1) mn = fminf(mn, __shfl_xor(mn, off, 64));
    if (t == 0) out[j] = scores[j] * expf(SIGMA * mn);
}

extern "C" void kernel_launch(void* const* d_in, const int* in_sizes, int n_in,
                              void* d_out, int out_size, void* d_ws, size_t ws_size,
                              hipStream_t stream) {
    const float* seg    = (const float*)d_in[0];   // (200,448,448) fp32 binary
    const float* scores = (const float*)d_in[1];   // (200,) fp32
    const int*   labels = (const int*)d_in[2];     // (200,) int32
    float* out = (float*)d_out;                    // (200,) fp32

    uint64_t* packed   = (uint64_t*)d_ws;
    uint16_t* packed16 = (uint16_t*)d_ws;
    int*      P        = (int*)((char*)d_ws + OFF_P);
    int*      SP       = (int*)((char*)d_ws + OFF_SP);
    float*    DTf      = (float*)((char*)d_ws + OFF_DT);
    float*    comp     = (float*)((char*)d_ws + OFF_CMP);

    {
        dim3 grid(49, N_INST);
        pack_kernel<<<grid, 256, 0, stream>>>(seg, packed16);
    }
    pair_kernel<<<(NTILE * NCHUNK + 3) / 4, 256, 0, stream>>>(packed, P, SP);
    iou_kernel<<<N_INST, 64, 0, stream>>>(P, SP, labels, DTf);
    comp_kernel<<<N_INST, 64, 0, stream>>>(DTf, comp);
    finalize_kernel<<<N_INST, 64, 0, stream>>>(DTf, comp, scores, out);
}